// Round 1
// baseline (636.925 us; speedup 1.0000x reference)
//
#include <hip/hip_runtime.h>
#include <hip/hip_bf16.h>

#define DMODEL 768
#define DINNER 1536
#define DSTATE 32
#define NHEADS 24
#define HEADDIM 64
#define CONVDIM 1600
#define DINPROJ 3160
#define SEQ 512
#define MROWS 1024   // B*SEQ = 2*512

// ---------------- block reduce (256 threads = 4 waves) ----------------
__device__ __forceinline__ float block_reduce_sum(float v, float* ws4) {
#pragma unroll
  for (int o = 32; o > 0; o >>= 1) v += __shfl_xor(v, o, 64);
  int wid = threadIdx.x >> 6;
  if ((threadIdx.x & 63) == 0) ws4[wid] = v;
  __syncthreads();
  return ws4[0] + ws4[1] + ws4[2] + ws4[3];
}

// ---------------- input RMSNorm: x[1024][768] -> h ----------------
__global__ __launch_bounds__(256) void rmsnorm_in_kernel(
    const float* __restrict__ x, const float* __restrict__ w, float* __restrict__ h) {
  __shared__ float ws4[4];
  int m = blockIdx.x;
  const float* xr = x + (size_t)m * DMODEL;
  float v[3];
  float ss = 0.f;
#pragma unroll
  for (int i = 0; i < 3; ++i) {
    v[i] = xr[threadIdx.x + i * 256];
    ss += v[i] * v[i];
  }
  ss = block_reduce_sum(ss, ws4);
  float sc = rsqrtf(ss / (float)DMODEL + 1e-5f);
  float* hr = h + (size_t)m * DMODEL;
#pragma unroll
  for (int i = 0; i < 3; ++i) {
    int c = threadIdx.x + i * 256;
    hr[c] = v[i] * sc * w[c];
  }
}

// ---------------- generic tiled fp32 GEMM: C[M,N] = A[M,K] @ B[N,K]^T ----------------
// REV_A: read A row with time-reversal within each batch of SEQ rows.
// ADD_X: C = A@B^T + X
#define BM 64
#define BN 64
#define BK 16

template <bool REV_A, bool ADD_X>
__global__ __launch_bounds__(256) void gemm_tn(
    const float* __restrict__ A, int lda,
    const float* __restrict__ Bw, int ldb,
    float* __restrict__ C, int ldc,
    const float* __restrict__ X, int ldx,
    int M, int N, int K) {
  __shared__ float As[BK][BM + 4];
  __shared__ float Bs[BK][BN + 4];
  int t = threadIdx.x;
  int n0 = blockIdx.x * BN;
  int m0 = blockIdx.y * BM;
  int tm = t >> 4;
  int tn = t & 15;
  int lr = t >> 2;          // 0..63 row within tile
  int lk = (t & 3) * 4;     // k offset within BK

  int am = m0 + lr;
  if (REV_A) am = (am & ~(SEQ - 1)) + (SEQ - 1 - (am & (SEQ - 1)));
  const float* Aptr = A + (size_t)am * lda + lk;
  int bn = n0 + lr;
  bool bvalid = bn < N;
  const float* Bptr = Bw + (size_t)(bvalid ? bn : 0) * ldb + lk;

  float acc[4][4] = {};
  for (int k0 = 0; k0 < K; k0 += BK) {
    float4 av = *(const float4*)(Aptr + k0);
    float4 bv;
    if (bvalid) bv = *(const float4*)(Bptr + k0);
    else { bv.x = bv.y = bv.z = bv.w = 0.f; }
    __syncthreads();
    As[lk + 0][lr] = av.x; As[lk + 1][lr] = av.y; As[lk + 2][lr] = av.z; As[lk + 3][lr] = av.w;
    Bs[lk + 0][lr] = bv.x; Bs[lk + 1][lr] = bv.y; Bs[lk + 2][lr] = bv.z; Bs[lk + 3][lr] = bv.w;
    __syncthreads();
#pragma unroll
    for (int kk = 0; kk < BK; ++kk) {
      float4 af = *(const float4*)&As[kk][tm * 4];
      float4 bf = *(const float4*)&Bs[kk][tn * 4];
      float a0 = af.x, a1 = af.y, a2 = af.z, a3 = af.w;
      float b0 = bf.x, b1 = bf.y, b2 = bf.z, b3 = bf.w;
      acc[0][0] = fmaf(a0, b0, acc[0][0]); acc[0][1] = fmaf(a0, b1, acc[0][1]);
      acc[0][2] = fmaf(a0, b2, acc[0][2]); acc[0][3] = fmaf(a0, b3, acc[0][3]);
      acc[1][0] = fmaf(a1, b0, acc[1][0]); acc[1][1] = fmaf(a1, b1, acc[1][1]);
      acc[1][2] = fmaf(a1, b2, acc[1][2]); acc[1][3] = fmaf(a1, b3, acc[1][3]);
      acc[2][0] = fmaf(a2, b0, acc[2][0]); acc[2][1] = fmaf(a2, b1, acc[2][1]);
      acc[2][2] = fmaf(a2, b2, acc[2][2]); acc[2][3] = fmaf(a2, b3, acc[2][3]);
      acc[3][0] = fmaf(a3, b0, acc[3][0]); acc[3][1] = fmaf(a3, b1, acc[3][1]);
      acc[3][2] = fmaf(a3, b2, acc[3][2]); acc[3][3] = fmaf(a3, b3, acc[3][3]);
    }
  }
#pragma unroll
  for (int i = 0; i < 4; ++i) {
#pragma unroll
    for (int j = 0; j < 4; ++j) {
      int m = m0 + tm * 4 + i;
      int n = n0 + tn * 4 + j;
      if (n < N) {
        float v = acc[i][j];
        if (ADD_X) v += X[(size_t)m * ldx + n];
        C[(size_t)m * ldc + n] = v;
      }
    }
  }
}

// ---------------- causal depthwise conv + silu + dt softplus/decay ----------------
// zx: [1024][3160]  (z | xBC | dt_raw)
// xbc out: [1024][1600], dta out: [1024][48] (dt | a=exp(dt*A))
__global__ __launch_bounds__(256) void conv_dt_kernel(
    const float* __restrict__ zx, const float* __restrict__ cw, const float* __restrict__ cb,
    const float* __restrict__ dt_bias, const float* __restrict__ A_log,
    float* __restrict__ xbc, float* __restrict__ dta) {
  int m = blockIdx.x;
  int l = m & (SEQ - 1);
  const float* zrow = zx + (size_t)m * DINPROJ + DINNER;  // xBC section
  for (int c = threadIdx.x; c < CONVDIM; c += 256) {
    float acc = cb[c];
#pragma unroll
    for (int j = 0; j < 4; ++j) {
      int ll = l - 3 + j;
      if (ll >= 0) acc = fmaf(zrow[(size_t)(j - 3) * DINPROJ + c], cw[c * 4 + j], acc);
    }
    float s = acc / (1.f + expf(-acc));  // silu
    xbc[(size_t)m * CONVDIM + c] = s;
  }
  if (threadIdx.x < NHEADS) {
    int hh = threadIdx.x;
    float v = zx[(size_t)m * DINPROJ + DINNER + CONVDIM + hh] + dt_bias[hh];
    float dt = (v > 20.f) ? v : log1pf(expf(v));
    float A = -expf(A_log[hh]);
    dta[(size_t)m * 48 + hh] = dt;
    dta[(size_t)m * 48 + NHEADS + hh] = expf(dt * A);
  }
}

// ---------------- selective scan ----------------
// grid: B*NHEADS = 48 blocks, 256 threads. thread t: p = t>>2 (0..63), q = t&3, n = q*8+j (j=0..7)
#define SCT 16  // timesteps per chunk
__global__ __launch_bounds__(256) void scan_kernel(
    const float* __restrict__ xbc,  // [1024][1600]
    const float* __restrict__ dta,  // [1024][48]
    const float* __restrict__ Dp,   // [24]
    float* __restrict__ y) {        // [1024][1536]
  __shared__ float xs[2][SCT][64];
  __shared__ float bcs[2][SCT][64];
  __shared__ float das[2][SCT][2];
  int bb = blockIdx.x / NHEADS;
  int hd = blockIdx.x % NHEADS;
  int t = threadIdx.x;
  int p = t >> 2, q = t & 3;
  int rowbase = bb * SEQ;
  const float* xrow = xbc + (size_t)rowbase * CONVDIM + hd * HEADDIM;
  const float* bcrow = xbc + (size_t)rowbase * CONVDIM + DINNER;
  float Dv = Dp[hd];
  float hst[8];
#pragma unroll
  for (int j = 0; j < 8; ++j) hst[j] = 0.f;

  int ls = t >> 4;            // step 0..15 for loading
  int lcol = (t & 15) * 4;    // col 0..60

  // preload chunk 0
  float4 xv = *(const float4*)(xrow + (size_t)ls * CONVDIM + lcol);
  float4 bcv = *(const float4*)(bcrow + (size_t)ls * CONVDIM + lcol);
  float dv = 0.f;
  if (t < 32) dv = dta[(size_t)(rowbase + (t & 15)) * 48 + (t >> 4) * NHEADS + hd];
  *(float4*)&xs[0][ls][lcol] = xv;
  *(float4*)&bcs[0][ls][lcol] = bcv;
  if (t < 32) das[0][t & 15][t >> 4] = dv;
  __syncthreads();

  int cur = 0;
  const int NCH = SEQ / SCT;  // 32
  for (int c = 0; c < NCH; ++c) {
    float4 xv2, bcv2;
    float dv2 = 0.f;
    if (c + 1 < NCH) {
      int mrow = (c + 1) * SCT + ls;
      xv2 = *(const float4*)(xrow + (size_t)mrow * CONVDIM + lcol);
      bcv2 = *(const float4*)(bcrow + (size_t)mrow * CONVDIM + lcol);
      if (t < 32) dv2 = dta[(size_t)(rowbase + (c + 1) * SCT + (t & 15)) * 48 + (t >> 4) * NHEADS + hd];
    }
#pragma unroll
    for (int s = 0; s < SCT; ++s) {
      float xp = xs[cur][s][p];
      float4 B0 = *(const float4*)&bcs[cur][s][q * 8];
      float4 B1 = *(const float4*)&bcs[cur][s][q * 8 + 4];
      float4 C0 = *(const float4*)&bcs[cur][s][32 + q * 8];
      float4 C1 = *(const float4*)&bcs[cur][s][32 + q * 8 + 4];
      float dt_s = das[cur][s][0];
      float a_s = das[cur][s][1];
      float cx = dt_s * xp;
      float acc = 0.f;
      float Bv[8] = {B0.x, B0.y, B0.z, B0.w, B1.x, B1.y, B1.z, B1.w};
      float Cv[8] = {C0.x, C0.y, C0.z, C0.w, C1.x, C1.y, C1.z, C1.w};
#pragma unroll
      for (int j = 0; j < 8; ++j) {
        hst[j] = fmaf(a_s, hst[j], cx * Bv[j]);
        acc = fmaf(hst[j], Cv[j], acc);
      }
      acc += __shfl_xor(acc, 1, 64);
      acc += __shfl_xor(acc, 2, 64);
      if (q == 0) {
        y[(size_t)(rowbase + c * SCT + s) * DINNER + hd * HEADDIM + p] = fmaf(Dv, xp, acc);
      }
    }
    if (c + 1 < NCH) {
      int nxt = cur ^ 1;
      *(float4*)&xs[nxt][ls][lcol] = xv2;
      *(float4*)&bcs[nxt][ls][lcol] = bcv2;
      if (t < 32) das[nxt][t & 15][t >> 4] = dv2;
      __syncthreads();
      cur = nxt;
    }
  }
}

// ---------------- gated RMSNorm: yn = rmsnorm(y * silu(z)) * nw ----------------
// writes into yn buffer with leading dim 1600 (reuses xbc buffer); REV reverses output row.
template <bool REV>
__global__ __launch_bounds__(256) void gated_norm_kernel(
    const float* __restrict__ y,   // [1024][1536]
    const float* __restrict__ zx,  // [1024][3160], z = cols 0..1535
    const float* __restrict__ nw,  // [1536]
    float* __restrict__ yn) {      // [1024][1600]
  __shared__ float ws4[4];
  int m = blockIdx.x;
  float g[6];
  float ss = 0.f;
#pragma unroll
  for (int i = 0; i < 6; ++i) {
    int c = threadIdx.x + i * 256;
    float yv = y[(size_t)m * DINNER + c];
    float zv = zx[(size_t)m * DINPROJ + c];
    float gg = yv * (zv / (1.f + expf(-zv)));
    g[i] = gg;
    ss += gg * gg;
  }
  ss = block_reduce_sum(ss, ws4);
  float sc = rsqrtf(ss / (float)DINNER + 1e-5f);
  int mo = REV ? ((m & ~(SEQ - 1)) + (SEQ - 1 - (m & (SEQ - 1)))) : m;
#pragma unroll
  for (int i = 0; i < 6; ++i) {
    int c = threadIdx.x + i * 256;
    yn[(size_t)mo * CONVDIM + c] = g[i] * sc * nw[c];
  }
}

// ---------------- launch ----------------
extern "C" void kernel_launch(void* const* d_in, const int* in_sizes, int n_in,
                              void* d_out, int out_size, void* d_ws, size_t ws_size,
                              hipStream_t stream) {
  const float* x = (const float*)d_in[0];
  const float* norm_w = (const float*)d_in[1];
  const float* in_w[2] = {(const float*)d_in[2], (const float*)d_in[10]};
  const float* conv_w[2] = {(const float*)d_in[3], (const float*)d_in[11]};
  const float* conv_b[2] = {(const float*)d_in[4], (const float*)d_in[12]};
  const float* dt_bias[2] = {(const float*)d_in[5], (const float*)d_in[13]};
  const float* A_log[2] = {(const float*)d_in[6], (const float*)d_in[14]};
  const float* Dp[2] = {(const float*)d_in[7], (const float*)d_in[15]};
  const float* nw[2] = {(const float*)d_in[8], (const float*)d_in[16]};
  const float* out_w[2] = {(const float*)d_in[9], (const float*)d_in[17]};
  const float* proj_w = (const float*)d_in[18];
  float* out = (float*)d_out;

  float* ws = (float*)d_ws;
  float* h = ws;                                  // 1024*768   = 786432
  float* zx = h + (size_t)MROWS * DMODEL;         // 1024*3160  = 3235840
  float* xbc = zx + (size_t)MROWS * DINPROJ;      // 1024*1600  = 1638400 (also yn)
  float* dta = xbc + (size_t)MROWS * CONVDIM;     // 1024*48    = 49152
  float* y = dta + (size_t)MROWS * 48;            // 1024*1536  = 1572864
  float* cat = y + (size_t)MROWS * DINNER;        // 1024*1536  = 1572864

  rmsnorm_in_kernel<<<MROWS, 256, 0, stream>>>(x, norm_w, h);

  for (int dir = 0; dir < 2; ++dir) {
    // in_proj: zx = h(rev?) @ in_w^T   [1024,3160]
    dim3 g1((DINPROJ + BN - 1) / BN, MROWS / BM);
    if (dir == 0)
      gemm_tn<false, false><<<g1, 256, 0, stream>>>(h, DMODEL, in_w[dir], DMODEL, zx, DINPROJ,
                                                    nullptr, 0, MROWS, DINPROJ, DMODEL);
    else
      gemm_tn<true, false><<<g1, 256, 0, stream>>>(h, DMODEL, in_w[dir], DMODEL, zx, DINPROJ,
                                                   nullptr, 0, MROWS, DINPROJ, DMODEL);

    conv_dt_kernel<<<MROWS, 256, 0, stream>>>(zx, conv_w[dir], conv_b[dir], dt_bias[dir],
                                              A_log[dir], xbc, dta);

    scan_kernel<<<2 * NHEADS, 256, 0, stream>>>(xbc, dta, Dp[dir], y);

    // gated norm -> yn (reuse xbc buffer, ld=1600), reversing rows for bwd dir
    if (dir == 0)
      gated_norm_kernel<false><<<MROWS, 256, 0, stream>>>(y, zx, nw[dir], xbc);
    else
      gated_norm_kernel<true><<<MROWS, 256, 0, stream>>>(y, zx, nw[dir], xbc);

    // out_proj: cat[:, dir*768 : dir*768+768] = yn @ out_w^T
    dim3 g2(DMODEL / BN, MROWS / BM);
    gemm_tn<false, false><<<g2, 256, 0, stream>>>(xbc, CONVDIM, out_w[dir], DINNER,
                                                  cat + dir * DMODEL, DINNER, nullptr, 0,
                                                  MROWS, DMODEL, DINNER);
  }

  // final: out = x + cat @ proj_w^T
  dim3 g3(DMODEL / BN, MROWS / BM);
  gemm_tn<false, true><<<g3, 256, 0, stream>>>(cat, DINNER, proj_w, DINNER, out, DMODEL,
                                               x, DMODEL, MROWS, DMODEL, DINNER);
}

// Round 2
// 399.378 us; speedup vs baseline: 1.5948x; 1.5948x over previous
//
#include <hip/hip_runtime.h>
#include <hip/hip_bf16.h>

#define DMODEL 768
#define DINNER 1536
#define DSTATE 32
#define NHEADS 24
#define HEADDIM 64
#define CONVDIM 1600
#define DINPROJ 3160
#define NPAD 3200
#define SEQ 512
#define MROWS 1024   // B*SEQ = 2*512

typedef __attribute__((ext_vector_type(8))) short bf16x8;
typedef __attribute__((ext_vector_type(4))) float f32x4;

__device__ __forceinline__ ushort f2bs(float v) {
  __hip_bfloat16 b = __float2bfloat16(v);
  return __builtin_bit_cast(unsigned short, b);
}

__device__ __forceinline__ void gld16(const void* g, const void* l) {
  __builtin_amdgcn_global_load_lds((const __attribute__((address_space(1))) void*)g,
                                   (__attribute__((address_space(3))) void*)l, 16, 0, 0);
}

// ---------------- block reduce (256 threads = 4 waves) ----------------
__device__ __forceinline__ float block_reduce_sum(float v, float* ws4) {
#pragma unroll
  for (int o = 32; o > 0; o >>= 1) v += __shfl_xor(v, o, 64);
  int wid = threadIdx.x >> 6;
  if ((threadIdx.x & 63) == 0) ws4[wid] = v;
  __syncthreads();
  return ws4[0] + ws4[1] + ws4[2] + ws4[3];
}

// ---------------- fp32 -> bf16 weight convert (with zero padding) ----------------
__global__ __launch_bounds__(256) void f2b_kernel(const float* __restrict__ s,
                                                  ushort* __restrict__ d, int ne, int npad) {
  int i = (blockIdx.x * 256 + threadIdx.x) * 4;
  if (i >= npad) return;
  if (i + 3 < ne) {
    float4 v = *(const float4*)(s + i);
    d[i + 0] = f2bs(v.x); d[i + 1] = f2bs(v.y); d[i + 2] = f2bs(v.z); d[i + 3] = f2bs(v.w);
  } else {
#pragma unroll
    for (int j = 0; j < 4; ++j) d[i + j] = (i + j < ne) ? f2bs(s[i + j]) : (ushort)0;
  }
}

// ---------------- input RMSNorm: x[1024][768] -> h (bf16) ----------------
__global__ __launch_bounds__(256) void rmsnorm_in_kernel(
    const float* __restrict__ x, const float* __restrict__ w, ushort* __restrict__ h) {
  __shared__ float ws4[4];
  int m = blockIdx.x;
  const float* xr = x + (size_t)m * DMODEL;
  float v[3];
  float ss = 0.f;
#pragma unroll
  for (int i = 0; i < 3; ++i) {
    v[i] = xr[threadIdx.x + i * 256];
    ss += v[i] * v[i];
  }
  ss = block_reduce_sum(ss, ws4);
  float sc = rsqrtf(ss / (float)DMODEL + 1e-5f);
  ushort* hr = h + (size_t)m * DMODEL;
#pragma unroll
  for (int i = 0; i < 3; ++i) {
    int c = threadIdx.x + i * 256;
    hr[c] = f2bs(v[i] * sc * w[c]);
  }
}

// ---------------- bf16 MFMA GEMM: C[M,N] = A[M,K] @ Bw[N,K]^T ----------------
// 128x128 tile, BK=32, 4 waves (2x2 of 64x64), global_load_lds staging.
template <bool REV_A, bool ADD_X, bool OUT_BF16>
__global__ __launch_bounds__(256) void gemm_mfma(
    const ushort* __restrict__ A, int lda,
    const ushort* __restrict__ Bw, int ldb,
    void* __restrict__ Cout, int ldc,
    const float* __restrict__ X, int ldx,
    int Nlog, int K) {
  __shared__ ushort As[128 * 32];
  __shared__ ushort Bs[128 * 32];
  const int t = threadIdx.x;
  const int w = t >> 6, l = t & 63;
  const int m0 = blockIdx.y * 128, n0 = blockIdx.x * 128;
  const int wr = w >> 1, wc = w & 1;
  const int fr = l & 15, fq = l >> 4;
  const int sr = l >> 2;
  const int sc = (l & 3) * 8;

  f32x4 acc[4][4];
#pragma unroll
  for (int m = 0; m < 4; ++m)
#pragma unroll
    for (int n = 0; n < 4; ++n) acc[m][n] = (f32x4){0.f, 0.f, 0.f, 0.f};

  for (int k0 = 0; k0 < K; k0 += 32) {
    __syncthreads();
#pragma unroll
    for (int r = 0; r < 2; ++r) {
      int row = (r * 4 + w) * 16 + sr;
      int am = m0 + row;
      if (REV_A) am = (am & ~(SEQ - 1)) + ((SEQ - 1) - (am & (SEQ - 1)));
      gld16(A + (size_t)am * lda + k0 + sc, (const char*)As + (r * 4 + w) * 1024);
      gld16(Bw + (size_t)(n0 + row) * ldb + k0 + sc, (const char*)Bs + (r * 4 + w) * 1024);
    }
    __syncthreads();
    bf16x8 af[4], bfr[4];
#pragma unroll
    for (int m = 0; m < 4; ++m)
      af[m] = *(const bf16x8*)&As[(wr * 64 + m * 16 + fr) * 32 + fq * 8];
#pragma unroll
    for (int n = 0; n < 4; ++n)
      bfr[n] = *(const bf16x8*)&Bs[(wc * 64 + n * 16 + fr) * 32 + fq * 8];
#pragma unroll
    for (int m = 0; m < 4; ++m)
#pragma unroll
      for (int n = 0; n < 4; ++n)
        acc[m][n] = __builtin_amdgcn_mfma_f32_16x16x32_bf16(af[m], bfr[n], acc[m][n], 0, 0, 0);
  }

#pragma unroll
  for (int m = 0; m < 4; ++m) {
#pragma unroll
    for (int n = 0; n < 4; ++n) {
      int col = n0 + wc * 64 + n * 16 + fr;
      if (col < Nlog) {
#pragma unroll
        for (int j = 0; j < 4; ++j) {
          int row = m0 + wr * 64 + m * 16 + fq * 4 + j;
          float v = acc[m][n][j];
          if (ADD_X) v += X[(size_t)row * ldx + col];
          if (OUT_BF16)
            ((ushort*)Cout)[(size_t)row * ldc + col] = f2bs(v);
          else
            ((float*)Cout)[(size_t)row * ldc + col] = v;
        }
      }
    }
  }
}

// ---------------- causal depthwise conv + silu + dt softplus/decay ----------------
__global__ __launch_bounds__(256) void conv_dt_kernel(
    const float* __restrict__ zx, const float* __restrict__ cw, const float* __restrict__ cb,
    const float* __restrict__ dt_bias, const float* __restrict__ A_log,
    float* __restrict__ xbc, float* __restrict__ dta) {
  int m = blockIdx.x;
  int l = m & (SEQ - 1);
  const float* zrow = zx + (size_t)m * DINPROJ + DINNER;  // xBC section
  for (int c = threadIdx.x; c < CONVDIM; c += 256) {
    float acc = cb[c];
#pragma unroll
    for (int j = 0; j < 4; ++j) {
      int ll = l - 3 + j;
      if (ll >= 0) acc = fmaf(zrow[(size_t)(j - 3) * DINPROJ + c], cw[c * 4 + j], acc);
    }
    float s = acc / (1.f + expf(-acc));  // silu
    xbc[(size_t)m * CONVDIM + c] = s;
  }
  if (threadIdx.x < NHEADS) {
    int hh = threadIdx.x;
    float v = zx[(size_t)m * DINPROJ + DINNER + CONVDIM + hh] + dt_bias[hh];
    float dt = (v > 20.f) ? v : log1pf(expf(v));
    float A = -expf(A_log[hh]);
    dta[(size_t)m * 48 + hh] = dt;
    dta[(size_t)m * 48 + NHEADS + hh] = expf(dt * A);
  }
}

// ---------------- selective scan ----------------
#define SCT 16  // timesteps per chunk
__global__ __launch_bounds__(256) void scan_kernel(
    const float* __restrict__ xbc,  // [1024][1600]
    const float* __restrict__ dta,  // [1024][48]
    const float* __restrict__ Dp,   // [24]
    float* __restrict__ y) {        // [1024][1536]
  __shared__ float xs[2][SCT][64];
  __shared__ float bcs[2][SCT][64];
  __shared__ float das[2][SCT][2];
  int bb = blockIdx.x / NHEADS;
  int hd = blockIdx.x % NHEADS;
  int t = threadIdx.x;
  int p = t >> 2, q = t & 3;
  int rowbase = bb * SEQ;
  const float* xrow = xbc + (size_t)rowbase * CONVDIM + hd * HEADDIM;
  const float* bcrow = xbc + (size_t)rowbase * CONVDIM + DINNER;
  float Dv = Dp[hd];
  float hst[8];
#pragma unroll
  for (int j = 0; j < 8; ++j) hst[j] = 0.f;

  int ls = t >> 4;
  int lcol = (t & 15) * 4;

  float4 xv = *(const float4*)(xrow + (size_t)ls * CONVDIM + lcol);
  float4 bcv = *(const float4*)(bcrow + (size_t)ls * CONVDIM + lcol);
  float dv = 0.f;
  if (t < 32) dv = dta[(size_t)(rowbase + (t & 15)) * 48 + (t >> 4) * NHEADS + hd];
  *(float4*)&xs[0][ls][lcol] = xv;
  *(float4*)&bcs[0][ls][lcol] = bcv;
  if (t < 32) das[0][t & 15][t >> 4] = dv;
  __syncthreads();

  int cur = 0;
  const int NCH = SEQ / SCT;  // 32
  for (int c = 0; c < NCH; ++c) {
    float4 xv2, bcv2;
    float dv2 = 0.f;
    if (c + 1 < NCH) {
      int mrow = (c + 1) * SCT + ls;
      xv2 = *(const float4*)(xrow + (size_t)mrow * CONVDIM + lcol);
      bcv2 = *(const float4*)(bcrow + (size_t)mrow * CONVDIM + lcol);
      if (t < 32) dv2 = dta[(size_t)(rowbase + (c + 1) * SCT + (t & 15)) * 48 + (t >> 4) * NHEADS + hd];
    }
#pragma unroll
    for (int s = 0; s < SCT; ++s) {
      float xp = xs[cur][s][p];
      float4 B0 = *(const float4*)&bcs[cur][s][q * 8];
      float4 B1 = *(const float4*)&bcs[cur][s][q * 8 + 4];
      float4 C0 = *(const float4*)&bcs[cur][s][32 + q * 8];
      float4 C1 = *(const float4*)&bcs[cur][s][32 + q * 8 + 4];
      float dt_s = das[cur][s][0];
      float a_s = das[cur][s][1];
      float cx = dt_s * xp;
      float acc = 0.f;
      float Bv[8] = {B0.x, B0.y, B0.z, B0.w, B1.x, B1.y, B1.z, B1.w};
      float Cv[8] = {C0.x, C0.y, C0.z, C0.w, C1.x, C1.y, C1.z, C1.w};
#pragma unroll
      for (int j = 0; j < 8; ++j) {
        hst[j] = fmaf(a_s, hst[j], cx * Bv[j]);
        acc = fmaf(hst[j], Cv[j], acc);
      }
      acc += __shfl_xor(acc, 1, 64);
      acc += __shfl_xor(acc, 2, 64);
      if (q == 0) {
        y[(size_t)(rowbase + c * SCT + s) * DINNER + hd * HEADDIM + p] = fmaf(Dv, xp, acc);
      }
    }
    if (c + 1 < NCH) {
      int nxt = cur ^ 1;
      *(float4*)&xs[nxt][ls][lcol] = xv2;
      *(float4*)&bcs[nxt][ls][lcol] = bcv2;
      if (t < 32) das[nxt][t & 15][t >> 4] = dv2;
      __syncthreads();
      cur = nxt;
    }
  }
}

// ---------------- gated RMSNorm -> yn (bf16, ld 1536), optional row reversal ----------------
template <bool REV>
__global__ __launch_bounds__(256) void gated_norm_kernel(
    const float* __restrict__ y,   // [1024][1536]
    const float* __restrict__ zx,  // [1024][3160], z = cols 0..1535
    const float* __restrict__ nw,  // [1536]
    ushort* __restrict__ yn) {     // [1024][1536] bf16
  __shared__ float ws4[4];
  int m = blockIdx.x;
  float g[6];
  float ss = 0.f;
#pragma unroll
  for (int i = 0; i < 6; ++i) {
    int c = threadIdx.x + i * 256;
    float yv = y[(size_t)m * DINNER + c];
    float zv = zx[(size_t)m * DINPROJ + c];
    float gg = yv * (zv / (1.f + expf(-zv)));
    g[i] = gg;
    ss += gg * gg;
  }
  ss = block_reduce_sum(ss, ws4);
  float sc = rsqrtf(ss / (float)DINNER + 1e-5f);
  int mo = REV ? ((m & ~(SEQ - 1)) + (SEQ - 1 - (m & (SEQ - 1)))) : m;
#pragma unroll
  for (int i = 0; i < 6; ++i) {
    int c = threadIdx.x + i * 256;
    yn[(size_t)mo * DINNER + c] = f2bs(g[i] * sc * nw[c]);
  }
}

// ---------------- launch ----------------
extern "C" void kernel_launch(void* const* d_in, const int* in_sizes, int n_in,
                              void* d_out, int out_size, void* d_ws, size_t ws_size,
                              hipStream_t stream) {
  const float* x = (const float*)d_in[0];
  const float* norm_w = (const float*)d_in[1];
  const float* in_w[2] = {(const float*)d_in[2], (const float*)d_in[10]};
  const float* conv_w[2] = {(const float*)d_in[3], (const float*)d_in[11]};
  const float* conv_b[2] = {(const float*)d_in[4], (const float*)d_in[12]};
  const float* dt_bias[2] = {(const float*)d_in[5], (const float*)d_in[13]};
  const float* A_log[2] = {(const float*)d_in[6], (const float*)d_in[14]};
  const float* Dp[2] = {(const float*)d_in[7], (const float*)d_in[15]};
  const float* nw[2] = {(const float*)d_in[8], (const float*)d_in[16]};
  const float* out_w[2] = {(const float*)d_in[9], (const float*)d_in[17]};
  const float* proj_w = (const float*)d_in[18];
  float* out = (float*)d_out;

  char* p = (char*)d_ws;
  float* zx = (float*)p;            p += (size_t)MROWS * DINPROJ * 4;
  float* xbc = (float*)p;           p += (size_t)MROWS * CONVDIM * 4;
  float* dta = (float*)p;           p += (size_t)MROWS * 48 * 4;
  float* y = (float*)p;             p += (size_t)MROWS * DINNER * 4;
  ushort* h = (ushort*)p;           p += (size_t)MROWS * DMODEL * 2;
  ushort* yn = (ushort*)p;          p += (size_t)MROWS * DINNER * 2;
  ushort* cat = (ushort*)p;         p += (size_t)MROWS * DINNER * 2;
  ushort* wi[2];
  wi[0] = (ushort*)p;               p += (size_t)NPAD * DMODEL * 2;
  wi[1] = (ushort*)p;               p += (size_t)NPAD * DMODEL * 2;
  ushort* wo[2];
  wo[0] = (ushort*)p;               p += (size_t)DMODEL * DINNER * 2;
  wo[1] = (ushort*)p;               p += (size_t)DMODEL * DINNER * 2;
  ushort* wp = (ushort*)p;          p += (size_t)DMODEL * DINNER * 2;

  // weight conversions
  {
    int ne = DINPROJ * DMODEL, np = NPAD * DMODEL;
    f2b_kernel<<<(np / 4 + 255) / 256, 256, 0, stream>>>(in_w[0], wi[0], ne, np);
    f2b_kernel<<<(np / 4 + 255) / 256, 256, 0, stream>>>(in_w[1], wi[1], ne, np);
    int ne2 = DMODEL * DINNER;
    f2b_kernel<<<(ne2 / 4 + 255) / 256, 256, 0, stream>>>(out_w[0], wo[0], ne2, ne2);
    f2b_kernel<<<(ne2 / 4 + 255) / 256, 256, 0, stream>>>(out_w[1], wo[1], ne2, ne2);
    f2b_kernel<<<(ne2 / 4 + 255) / 256, 256, 0, stream>>>(proj_w, wp, ne2, ne2);
  }

  rmsnorm_in_kernel<<<MROWS, 256, 0, stream>>>(x, norm_w, h);

  for (int dir = 0; dir < 2; ++dir) {
    // in_proj: zx = h(rev?) @ in_w^T  [1024,3160] fp32 out
    dim3 g1(NPAD / 128, MROWS / 128);
    if (dir == 0)
      gemm_mfma<false, false, false><<<g1, 256, 0, stream>>>(h, DMODEL, wi[dir], DMODEL,
                                                             zx, DINPROJ, nullptr, 0,
                                                             DINPROJ, DMODEL);
    else
      gemm_mfma<true, false, false><<<g1, 256, 0, stream>>>(h, DMODEL, wi[dir], DMODEL,
                                                            zx, DINPROJ, nullptr, 0,
                                                            DINPROJ, DMODEL);

    conv_dt_kernel<<<MROWS, 256, 0, stream>>>(zx, conv_w[dir], conv_b[dir], dt_bias[dir],
                                              A_log[dir], xbc, dta);

    scan_kernel<<<2 * NHEADS, 256, 0, stream>>>(xbc, dta, Dp[dir], y);

    if (dir == 0)
      gated_norm_kernel<false><<<MROWS, 256, 0, stream>>>(y, zx, nw[dir], yn);
    else
      gated_norm_kernel<true><<<MROWS, 256, 0, stream>>>(y, zx, nw[dir], yn);

    // out_proj: cat[:, dir*768 +: 768] = yn @ out_w^T  (bf16 out)
    dim3 g2(DMODEL / 128, MROWS / 128);
    gemm_mfma<false, false, true><<<g2, 256, 0, stream>>>(yn, DINNER, wo[dir], DINNER,
                                                          cat + dir * DMODEL, DINNER,
                                                          nullptr, 0, DMODEL, DINNER);
  }

  // final: out = x + cat @ proj_w^T  (fp32 out)
  dim3 g3(DMODEL / 128, MROWS / 128);
  gemm_mfma<false, true, false><<<g3, 256, 0, stream>>>(cat, DINNER, wp, DINNER,
                                                        out, DMODEL, x, DMODEL,
                                                        DMODEL, DINNER);
}

// Round 3
// 182.822 us; speedup vs baseline: 3.4839x; 2.1845x over previous
//
#include <hip/hip_runtime.h>
#include <hip/hip_bf16.h>

#define DMODEL 768
#define DINNER 1536
#define DSTATE 32
#define NHEADS 24
#define HEADDIM 64
#define CONVDIM 1600
#define DINPROJ 3160
#define NPAD 3200
#define SEQ 512
#define MROWS 1024   // B*SEQ = 2*512
#define CL 64        // chunk length
#define NCH 8        // chunks per sequence

typedef __attribute__((ext_vector_type(8))) short bf16x8;
typedef __attribute__((ext_vector_type(4))) float f32x4;

__device__ __forceinline__ ushort f2bs(float v) {
  __hip_bfloat16 b = __float2bfloat16(v);
  return __builtin_bit_cast(unsigned short, b);
}

__device__ __forceinline__ void gld16(const void* g, const void* l) {
  __builtin_amdgcn_global_load_lds((const __attribute__((address_space(1))) void*)g,
                                   (__attribute__((address_space(3))) void*)l, 16, 0, 0);
}

__device__ __forceinline__ float block_reduce_sum(float v, float* ws4) {
#pragma unroll
  for (int o = 32; o > 0; o >>= 1) v += __shfl_xor(v, o, 64);
  int wid = threadIdx.x >> 6;
  if ((threadIdx.x & 63) == 0) ws4[wid] = v;
  __syncthreads();
  return ws4[0] + ws4[1] + ws4[2] + ws4[3];
}

// ---------------- fp32 -> bf16 weight convert (with zero padding) ----------------
__global__ __launch_bounds__(256) void f2b_kernel(const float* __restrict__ s,
                                                  ushort* __restrict__ d, int ne, int npad) {
  int i = (blockIdx.x * 256 + threadIdx.x) * 4;
  if (i >= npad) return;
  if (i + 3 < ne) {
    float4 v = *(const float4*)(s + i);
    d[i + 0] = f2bs(v.x); d[i + 1] = f2bs(v.y); d[i + 2] = f2bs(v.z); d[i + 3] = f2bs(v.w);
  } else {
#pragma unroll
    for (int j = 0; j < 4; ++j) d[i + j] = (i + j < ne) ? f2bs(s[i + j]) : (ushort)0;
  }
}

// ---------------- input RMSNorm: x[1024][768] -> h (bf16) ----------------
__global__ __launch_bounds__(256) void rmsnorm_in_kernel(
    const float* __restrict__ x, const float* __restrict__ w, ushort* __restrict__ h) {
  __shared__ float ws4[4];
  int m = blockIdx.x;
  const float* xr = x + (size_t)m * DMODEL;
  float v[3];
  float ss = 0.f;
#pragma unroll
  for (int i = 0; i < 3; ++i) {
    v[i] = xr[threadIdx.x + i * 256];
    ss += v[i] * v[i];
  }
  ss = block_reduce_sum(ss, ws4);
  float sc = rsqrtf(ss / (float)DMODEL + 1e-5f);
  ushort* hr = h + (size_t)m * DMODEL;
#pragma unroll
  for (int i = 0; i < 3; ++i) {
    int c = threadIdx.x + i * 256;
    hr[c] = f2bs(v[i] * sc * w[c]);
  }
}

// ---------------- bf16 MFMA GEMM: C[M,N] = A[M,K] @ Bw[N,K]^T (z-batched) ----------------
// 128x128 tile, BK=32, 4 waves; all dims multiples of 128 (cols padded where needed).
template <bool ADD_X, bool OUT_BF16>
__global__ __launch_bounds__(256) void gemm_mfma(
    const ushort* __restrict__ A, int lda, size_t aStrideZ,
    const ushort* __restrict__ Bw, int ldb, size_t bStrideZ,
    void* __restrict__ Cout, int ldc, size_t cStrideZ,
    const float* __restrict__ X, int ldx, int K) {
  __shared__ ushort As[128 * 32];
  __shared__ ushort Bs[128 * 32];
  const int t = threadIdx.x;
  const int w = t >> 6, l = t & 63;
  const int m0 = blockIdx.y * 128, n0 = blockIdx.x * 128;
  const int wr = w >> 1, wc = w & 1;
  const int fr = l & 15, fq = l >> 4;
  const int sr = l >> 2;
  const int sc = (l & 3) * 8;

  const ushort* Ap = A + (size_t)blockIdx.z * aStrideZ;
  const ushort* Bp = Bw + (size_t)blockIdx.z * bStrideZ;

  f32x4 acc[4][4];
#pragma unroll
  for (int m = 0; m < 4; ++m)
#pragma unroll
    for (int n = 0; n < 4; ++n) acc[m][n] = (f32x4){0.f, 0.f, 0.f, 0.f};

  for (int k0 = 0; k0 < K; k0 += 32) {
    __syncthreads();
#pragma unroll
    for (int r = 0; r < 2; ++r) {
      int row = (r * 4 + w) * 16 + sr;
      gld16(Ap + (size_t)(m0 + row) * lda + k0 + sc, (const char*)As + (r * 4 + w) * 1024);
      gld16(Bp + (size_t)(n0 + row) * ldb + k0 + sc, (const char*)Bs + (r * 4 + w) * 1024);
    }
    __syncthreads();
    bf16x8 af[4], bfr[4];
#pragma unroll
    for (int m = 0; m < 4; ++m)
      af[m] = *(const bf16x8*)&As[(wr * 64 + m * 16 + fr) * 32 + fq * 8];
#pragma unroll
    for (int n = 0; n < 4; ++n)
      bfr[n] = *(const bf16x8*)&Bs[(wc * 64 + n * 16 + fr) * 32 + fq * 8];
#pragma unroll
    for (int m = 0; m < 4; ++m)
#pragma unroll
      for (int n = 0; n < 4; ++n)
        acc[m][n] = __builtin_amdgcn_mfma_f32_16x16x32_bf16(af[m], bfr[n], acc[m][n], 0, 0, 0);
  }

#pragma unroll
  for (int m = 0; m < 4; ++m) {
#pragma unroll
    for (int n = 0; n < 4; ++n) {
      int col = n0 + wc * 64 + n * 16 + fr;
#pragma unroll
      for (int j = 0; j < 4; ++j) {
        int row = m0 + wr * 64 + m * 16 + fq * 4 + j;
        float v = acc[m][n][j];
        if (ADD_X) v += X[(size_t)row * ldx + col];
        if (OUT_BF16)
          ((ushort*)Cout + (size_t)blockIdx.z * cStrideZ)[(size_t)row * ldc + col] = f2bs(v);
        else
          ((float*)Cout + (size_t)blockIdx.z * cStrideZ)[(size_t)row * ldc + col] = v;
      }
    }
  }
}

// ---------------- causal (fwd) / anti-causal (bwd) depthwise conv + silu + dt ----------------
// zx: [1024][6400]  (dir*3200 + {z[1536] | xBC[1600] | dt[24] | pad})
// xbc: [2][1024][1600], dta: [2][1024][48] (dt | a)
__global__ __launch_bounds__(256) void conv_dt_kernel(
    const float* __restrict__ zx,
    const float* __restrict__ cw0, const float* __restrict__ cb0,
    const float* __restrict__ dtb0, const float* __restrict__ Al0,
    const float* __restrict__ cw1, const float* __restrict__ cb1,
    const float* __restrict__ dtb1, const float* __restrict__ Al1,
    float* __restrict__ xbc, float* __restrict__ dta) {
  int m = blockIdx.x;
  int dir = blockIdx.y;
  int l = m & (SEQ - 1);
  const float* cw = dir ? cw1 : cw0;
  const float* cb = dir ? cb1 : cb0;
  const float* zrow = zx + (size_t)m * 6400 + dir * 3200 + DINNER;  // xBC section
  float* xo = xbc + ((size_t)dir * MROWS + m) * CONVDIM;
  for (int c = threadIdx.x; c < CONVDIM; c += 256) {
    float acc = cb[c];
    if (dir == 0) {
#pragma unroll
      for (int d = 0; d < 4; ++d) {  // u[t-d] * w[3-d]
        if (l - d >= 0) acc = fmaf(zrow[-(size_t)d * 6400 + c], cw[c * 4 + 3 - d], acc);
      }
    } else {
#pragma unroll
      for (int d = 0; d < 4; ++d) {  // u[t+d] * w[3-d]
        if (l + d < SEQ) acc = fmaf(zrow[(size_t)d * 6400 + c], cw[c * 4 + 3 - d], acc);
      }
    }
    xo[c] = acc / (1.f + expf(-acc));  // silu
  }
  if (threadIdx.x < NHEADS) {
    int hh = threadIdx.x;
    const float* dtb = dir ? dtb1 : dtb0;
    const float* Al = dir ? Al1 : Al0;
    float v = zx[(size_t)m * 6400 + dir * 3200 + DINNER + CONVDIM + hh] + dtb[hh];
    float dt = (v > 20.f) ? v : log1pf(expf(v));
    float A = -expf(Al[hh]);
    dta[((size_t)dir * MROWS + m) * 48 + hh] = dt;
    dta[((size_t)dir * MROWS + m) * 48 + NHEADS + hh] = expf(dt * A);
  }
}

// ---------------- scan phase 1: per-chunk local end-state S_c and decay alpha_c ----------------
// grid (NCH, 48, 2): chunk c, bh (b*24+h), dir. sbuf: [(dir*48+bh)*8 + c][2048], abuf same idx.
__global__ __launch_bounds__(256) void scan_phase1(
    const float* __restrict__ xbc, const float* __restrict__ dta,
    float* __restrict__ sbuf, float* __restrict__ abuf) {
  __shared__ float xs[CL][64];
  __shared__ float bcs[CL][64];
  __shared__ float das[CL][2];
  int c = blockIdx.x, bh = blockIdx.y, dir = blockIdx.z;
  int b = bh / NHEADS, h = bh % NHEADS;
  int t = threadIdx.x, p = t >> 2, q = t & 3;
  const float* xb = xbc + ((size_t)dir * MROWS + b * SEQ) * CONVDIM;
  int lrow = t >> 4, lcol = (t & 15) * 4;
#pragma unroll
  for (int r = 0; r < 4; ++r) {
    int s = r * 16 + lrow;
    int tau = c * CL + s;
    int prow = dir ? (SEQ - 1 - tau) : tau;
    const float* rowp = xb + (size_t)prow * CONVDIM;
    *(float4*)&xs[s][lcol] = *(const float4*)(rowp + h * HEADDIM + lcol);
    *(float4*)&bcs[s][lcol] = *(const float4*)(rowp + DINNER + lcol);
  }
  if (t < 128) {
    int s = t >> 1, wsel = t & 1;
    int tau = c * CL + s;
    int prow = dir ? (SEQ - 1 - tau) : tau;
    das[s][wsel] = dta[((size_t)dir * MROWS + b * SEQ + prow) * 48 + wsel * NHEADS + h];
  }
  __syncthreads();
  float hst[8];
#pragma unroll
  for (int j = 0; j < 8; ++j) hst[j] = 0.f;
  float alpha = 1.f;
#pragma unroll 8
  for (int s = 0; s < CL; ++s) {
    float xp = xs[s][p];
    float dt_s = das[s][0], a_s = das[s][1];
    float cx = dt_s * xp;
    alpha *= a_s;
    float4 B0 = *(const float4*)&bcs[s][q * 8];
    float4 B1 = *(const float4*)&bcs[s][q * 8 + 4];
    float Bv[8] = {B0.x, B0.y, B0.z, B0.w, B1.x, B1.y, B1.z, B1.w};
#pragma unroll
    for (int j = 0; j < 8; ++j) hst[j] = fmaf(a_s, hst[j], cx * Bv[j]);
  }
  float* sp = sbuf + (((size_t)(dir * 48 + bh)) * NCH + c) * 2048 + p * 32 + q * 8;
#pragma unroll
  for (int j = 0; j < 8; ++j) sp[j] = hst[j];
  if (t == 0) abuf[(dir * 48 + bh) * NCH + c] = alpha;
}

// ---------------- scan phase 2: combine chunk states (in-place: sbuf[c] <- h0 entering c) ----------
__global__ __launch_bounds__(256) void scan_phase2(float* __restrict__ sbuf,
                                                   const float* __restrict__ abuf) {
  int g = blockIdx.x;  // dir*48+bh
  int t = threadIdx.x;
  float run[8];
#pragma unroll
  for (int j = 0; j < 8; ++j) run[j] = 0.f;
  size_t base = (size_t)g * NCH * 2048 + t * 8;
  for (int c = 0; c < NCH; ++c) {
    float* sp = sbuf + base + (size_t)c * 2048;
    float4 s0 = *(const float4*)sp;
    float4 s1 = *(const float4*)(sp + 4);
    float al = abuf[g * NCH + c];
    float4 r0 = {run[0], run[1], run[2], run[3]};
    float4 r1 = {run[4], run[5], run[6], run[7]};
    *(float4*)sp = r0;
    *(float4*)(sp + 4) = r1;
    float sv[8] = {s0.x, s0.y, s0.z, s0.w, s1.x, s1.y, s1.z, s1.w};
#pragma unroll
    for (int j = 0; j < 8; ++j) run[j] = fmaf(al, run[j], sv[j]);
  }
}

// ---------------- scan phase 3: per-chunk full recurrence from h0, write y ----------------
__global__ __launch_bounds__(256) void scan_phase3(
    const float* __restrict__ xbc, const float* __restrict__ dta,
    const float* __restrict__ sbuf,
    const float* __restrict__ Dp0, const float* __restrict__ Dp1,
    float* __restrict__ y) {  // [2][1024][1536]
  __shared__ float xs[CL][64];
  __shared__ float bcs[CL][64];
  __shared__ float das[CL][2];
  int c = blockIdx.x, bh = blockIdx.y, dir = blockIdx.z;
  int b = bh / NHEADS, h = bh % NHEADS;
  int t = threadIdx.x, p = t >> 2, q = t & 3;
  const float* xb = xbc + ((size_t)dir * MROWS + b * SEQ) * CONVDIM;
  int lrow = t >> 4, lcol = (t & 15) * 4;
#pragma unroll
  for (int r = 0; r < 4; ++r) {
    int s = r * 16 + lrow;
    int tau = c * CL + s;
    int prow = dir ? (SEQ - 1 - tau) : tau;
    const float* rowp = xb + (size_t)prow * CONVDIM;
    *(float4*)&xs[s][lcol] = *(const float4*)(rowp + h * HEADDIM + lcol);
    *(float4*)&bcs[s][lcol] = *(const float4*)(rowp + DINNER + lcol);
  }
  if (t < 128) {
    int s = t >> 1, wsel = t & 1;
    int tau = c * CL + s;
    int prow = dir ? (SEQ - 1 - tau) : tau;
    das[s][wsel] = dta[((size_t)dir * MROWS + b * SEQ + prow) * 48 + wsel * NHEADS + h];
  }
  float hst[8];
  {
    const float* sp = sbuf + (((size_t)(dir * 48 + bh)) * NCH + c) * 2048 + p * 32 + q * 8;
    float4 h0 = *(const float4*)sp;
    float4 h1 = *(const float4*)(sp + 4);
    hst[0] = h0.x; hst[1] = h0.y; hst[2] = h0.z; hst[3] = h0.w;
    hst[4] = h1.x; hst[5] = h1.y; hst[6] = h1.z; hst[7] = h1.w;
  }
  float Dv = (dir ? Dp1 : Dp0)[h];
  __syncthreads();
#pragma unroll 8
  for (int s = 0; s < CL; ++s) {
    float xp = xs[s][p];
    float dt_s = das[s][0], a_s = das[s][1];
    float cx = dt_s * xp;
    float4 B0 = *(const float4*)&bcs[s][q * 8];
    float4 B1 = *(const float4*)&bcs[s][q * 8 + 4];
    float4 C0 = *(const float4*)&bcs[s][32 + q * 8];
    float4 C1 = *(const float4*)&bcs[s][32 + q * 8 + 4];
    float Bv[8] = {B0.x, B0.y, B0.z, B0.w, B1.x, B1.y, B1.z, B1.w};
    float Cv[8] = {C0.x, C0.y, C0.z, C0.w, C1.x, C1.y, C1.z, C1.w};
    float acc = 0.f;
#pragma unroll
    for (int j = 0; j < 8; ++j) {
      hst[j] = fmaf(a_s, hst[j], cx * Bv[j]);
      acc = fmaf(hst[j], Cv[j], acc);
    }
    acc += __shfl_xor(acc, 1, 64);
    acc += __shfl_xor(acc, 2, 64);
    if (q == 0) {
      int tau = c * CL + s;
      int prow = dir ? (SEQ - 1 - tau) : tau;
      y[((size_t)dir * MROWS + b * SEQ + prow) * DINNER + h * HEADDIM + p] = fmaf(Dv, xp, acc);
    }
  }
}

// ---------------- gated RMSNorm -> yn (bf16) ----------------
__global__ __launch_bounds__(256) void gated_norm_kernel(
    const float* __restrict__ y,   // [2][1024][1536]
    const float* __restrict__ zx,  // [1024][6400]
    const float* __restrict__ nw0, const float* __restrict__ nw1,
    ushort* __restrict__ yn) {     // [2][1024][1536] bf16
  __shared__ float ws4[4];
  int m = blockIdx.x;
  int dir = blockIdx.y;
  const float* nw = dir ? nw1 : nw0;
  float g[6];
  float ss = 0.f;
#pragma unroll
  for (int i = 0; i < 6; ++i) {
    int c = threadIdx.x + i * 256;
    float yv = y[((size_t)dir * MROWS + m) * DINNER + c];
    float zv = zx[(size_t)m * 6400 + dir * 3200 + c];
    float gg = yv * (zv / (1.f + expf(-zv)));
    g[i] = gg;
    ss += gg * gg;
  }
  ss = block_reduce_sum(ss, ws4);
  float sc = rsqrtf(ss / (float)DINNER + 1e-5f);
#pragma unroll
  for (int i = 0; i < 6; ++i) {
    int c = threadIdx.x + i * 256;
    yn[((size_t)dir * MROWS + m) * DINNER + c] = f2bs(g[i] * sc * nw[c]);
  }
}

// ---------------- launch ----------------
extern "C" void kernel_launch(void* const* d_in, const int* in_sizes, int n_in,
                              void* d_out, int out_size, void* d_ws, size_t ws_size,
                              hipStream_t stream) {
  const float* x = (const float*)d_in[0];
  const float* norm_w = (const float*)d_in[1];
  const float* in_w[2] = {(const float*)d_in[2], (const float*)d_in[10]};
  const float* conv_w[2] = {(const float*)d_in[3], (const float*)d_in[11]};
  const float* conv_b[2] = {(const float*)d_in[4], (const float*)d_in[12]};
  const float* dt_bias[2] = {(const float*)d_in[5], (const float*)d_in[13]};
  const float* A_log[2] = {(const float*)d_in[6], (const float*)d_in[14]};
  const float* Dp[2] = {(const float*)d_in[7], (const float*)d_in[15]};
  const float* nw[2] = {(const float*)d_in[8], (const float*)d_in[16]};
  const float* out_w[2] = {(const float*)d_in[9], (const float*)d_in[17]};
  const float* proj_w = (const float*)d_in[18];
  float* out = (float*)d_out;

  char* p = (char*)d_ws;
  float* zx = (float*)p;    p += (size_t)MROWS * 6400 * 4;          // 26.2MB
  float* xbc = (float*)p;   p += (size_t)2 * MROWS * CONVDIM * 4;   // 13.1MB
  float* dta = (float*)p;   p += (size_t)2 * MROWS * 48 * 4;        // 0.4MB
  float* y = (float*)p;     p += (size_t)2 * MROWS * DINNER * 4;    // 12.6MB
  float* sbuf = (float*)p;  p += (size_t)96 * NCH * 2048 * 4;       // 6.3MB
  float* abuf = (float*)p;  p += (size_t)96 * NCH * 4;
  ushort* h = (ushort*)p;   p += (size_t)MROWS * DMODEL * 2;        // 1.6MB
  ushort* yn = (ushort*)p;  p += (size_t)2 * MROWS * DINNER * 2;    // 6.3MB
  ushort* cat = (ushort*)p; p += (size_t)MROWS * DINNER * 2;        // 3.1MB
  ushort* wi = (ushort*)p;  p += (size_t)2 * NPAD * DMODEL * 2;     // 9.8MB
  ushort* wo = (ushort*)p;  p += (size_t)2 * DMODEL * DINNER * 2;   // 4.7MB
  ushort* wp = (ushort*)p;  p += (size_t)DMODEL * DINNER * 2;       // 2.4MB

  // weight conversions (bf16, padded)
  {
    int ne = DINPROJ * DMODEL, np = NPAD * DMODEL;
    f2b_kernel<<<(np / 4 + 255) / 256, 256, 0, stream>>>(in_w[0], wi, ne, np);
    f2b_kernel<<<(np / 4 + 255) / 256, 256, 0, stream>>>(in_w[1], wi + (size_t)NPAD * DMODEL, ne, np);
    int ne2 = DMODEL * DINNER;
    f2b_kernel<<<(ne2 / 4 + 255) / 256, 256, 0, stream>>>(out_w[0], wo, ne2, ne2);
    f2b_kernel<<<(ne2 / 4 + 255) / 256, 256, 0, stream>>>(out_w[1], wo + (size_t)DMODEL * DINNER, ne2, ne2);
    f2b_kernel<<<(ne2 / 4 + 255) / 256, 256, 0, stream>>>(proj_w, wp, ne2, ne2);
  }

  rmsnorm_in_kernel<<<MROWS, 256, 0, stream>>>(x, norm_w, h);

  // in_proj both dirs: zx[1024][6400] = h @ [wi0|wi1]^T
  {
    dim3 g(6400 / 128, MROWS / 128, 1);
    gemm_mfma<false, false><<<g, 256, 0, stream>>>(h, DMODEL, 0, wi, DMODEL, 0,
                                                   zx, 6400, 0, nullptr, 0, DMODEL);
  }

  conv_dt_kernel<<<dim3(MROWS, 2), 256, 0, stream>>>(
      zx, conv_w[0], conv_b[0], dt_bias[0], A_log[0],
      conv_w[1], conv_b[1], dt_bias[1], A_log[1], xbc, dta);

  scan_phase1<<<dim3(NCH, 48, 2), 256, 0, stream>>>(xbc, dta, sbuf, abuf);
  scan_phase2<<<96, 256, 0, stream>>>(sbuf, abuf);
  scan_phase3<<<dim3(NCH, 48, 2), 256, 0, stream>>>(xbc, dta, sbuf, Dp[0], Dp[1], y);

  gated_norm_kernel<<<dim3(MROWS, 2), 256, 0, stream>>>(y, zx, nw[0], nw[1], yn);

  // out_proj both dirs: cat[:, dir*768 +: 768] = yn[dir] @ wo[dir]^T
  {
    dim3 g(DMODEL / 128, MROWS / 128, 2);
    gemm_mfma<false, true><<<g, 256, 0, stream>>>(
        yn, DINNER, (size_t)MROWS * DINNER, wo, DINNER, (size_t)DMODEL * DINNER,
        cat, DINNER, (size_t)DMODEL, nullptr, 0, DINNER);
  }

  // final: out = x + cat @ wp^T
  {
    dim3 g(DMODEL / 128, MROWS / 128, 1);
    gemm_mfma<true, false><<<g, 256, 0, stream>>>(cat, DINNER, 0, wp, DINNER, 0,
                                                  out, DMODEL, 0, x, DMODEL, DINNER);
  }
}

// Round 4
// 132.463 us; speedup vs baseline: 4.8083x; 1.3802x over previous
//
#include <hip/hip_runtime.h>
#include <hip/hip_bf16.h>

#define DMODEL 768
#define DINNER 1536
#define DSTATE 32
#define NHEADS 24
#define HEADDIM 64
#define CONVDIM 1600
#define DINPROJ 3160
#define NPAD 3200
#define SEQ 512
#define MROWS 1024   // B*SEQ = 2*512
#define CL 64        // chunk length
#define NCH 8        // chunks per sequence

typedef __attribute__((ext_vector_type(8))) short bf16x8;
typedef __attribute__((ext_vector_type(4))) float f32x4;

__device__ __forceinline__ ushort f2bs(float v) {
  __hip_bfloat16 b = __float2bfloat16(v);
  return __builtin_bit_cast(unsigned short, b);
}

__device__ __forceinline__ void gld16(const void* g, const void* l) {
  __builtin_amdgcn_global_load_lds((const __attribute__((address_space(1))) void*)g,
                                   (__attribute__((address_space(3))) void*)l, 16, 0, 0);
}

__device__ __forceinline__ float block_reduce_sum(float v, float* ws4) {
#pragma unroll
  for (int o = 32; o > 0; o >>= 1) v += __shfl_xor(v, o, 64);
  int wid = threadIdx.x >> 6;
  if ((threadIdx.x & 63) == 0) ws4[wid] = v;
  __syncthreads();
  return ws4[0] + ws4[1] + ws4[2] + ws4[3];
}

// ---------------- all weight conversions in ONE dispatch ----------------
// dest layout: wi[2][NPAD*DMODEL] | wo[2][DMODEL*DINNER] | wp[DMODEL*DINNER]
__global__ __launch_bounds__(256) void f2b_all(
    const float* __restrict__ s0, const float* __restrict__ s1,
    const float* __restrict__ s2, const float* __restrict__ s3,
    const float* __restrict__ s4, ushort* __restrict__ d) {
  constexpr size_t NP_IN = (size_t)NPAD * DMODEL;     // 2457600 (padded)
  constexpr size_t NE_IN = (size_t)DINPROJ * DMODEL;  // 2426880 (real)
  constexpr size_t NE_O = (size_t)DMODEL * DINNER;    // 1179648
  size_t i = ((size_t)blockIdx.x * 256 + threadIdx.x) * 4;
  const float* src;
  size_t off, ne;
  if (i < NP_IN) { src = s0; off = i; ne = NE_IN; }
  else if (i < 2 * NP_IN) { src = s1; off = i - NP_IN; ne = NE_IN; }
  else if (i < 2 * NP_IN + NE_O) { src = s2; off = i - 2 * NP_IN; ne = NE_O; }
  else if (i < 2 * NP_IN + 2 * NE_O) { src = s3; off = i - 2 * NP_IN - NE_O; ne = NE_O; }
  else if (i < 2 * NP_IN + 3 * NE_O) { src = s4; off = i - 2 * NP_IN - 2 * NE_O; ne = NE_O; }
  else return;
  ushort* dp = d + i;
  if (off + 3 < ne) {
    float4 v = *(const float4*)(src + off);
    dp[0] = f2bs(v.x); dp[1] = f2bs(v.y); dp[2] = f2bs(v.z); dp[3] = f2bs(v.w);
  } else {
#pragma unroll
    for (int j = 0; j < 4; ++j) dp[j] = (off + j < ne) ? f2bs(src[off + j]) : (ushort)0;
  }
}

// ---------------- input RMSNorm: x[1024][768] -> h (bf16) ----------------
__global__ __launch_bounds__(256) void rmsnorm_in_kernel(
    const float* __restrict__ x, const float* __restrict__ w, ushort* __restrict__ h) {
  __shared__ float ws4[4];
  int m = blockIdx.x;
  const float* xr = x + (size_t)m * DMODEL;
  float v[3];
  float ss = 0.f;
#pragma unroll
  for (int i = 0; i < 3; ++i) {
    v[i] = xr[threadIdx.x + i * 256];
    ss += v[i] * v[i];
  }
  ss = block_reduce_sum(ss, ws4);
  float sc = rsqrtf(ss / (float)DMODEL + 1e-5f);
  ushort* hr = h + (size_t)m * DMODEL;
#pragma unroll
  for (int i = 0; i < 3; ++i) {
    int c = threadIdx.x + i * 256;
    hr[c] = f2bs(v[i] * sc * w[c]);
  }
}

// ---------------- 2-phase double-buffered bf16 MFMA GEMM ----------------
// C[M,N] = A[M,K] @ Bw[N,K]^T, z-batched. 4 waves as 2x2, wave tile (BM/2)x(BN/2).
// One barrier per K-step; stage(k+1) issued BEFORE compute(k) so the
// global_load_lds latency hides under ds_read+MFMA (T3 minimum recipe).
template <int BM, int BN, bool ADD_X, bool OUT_BF16>
__global__ __launch_bounds__(256) void gemm2(
    const ushort* __restrict__ A, int lda, size_t aZ,
    const ushort* __restrict__ Bw, int ldb, size_t bZ,
    void* __restrict__ Cout, int ldc, size_t cZ,
    const float* __restrict__ X, int ldx, int K) {
  constexpr int AG = BM / 16;  // 1KB stage groups (16 rows x 32 cols bf16)
  constexpr int BG = BN / 16;
  constexpr int MR = BM / 32;  // 16x16 frags per wave (M)
  constexpr int NR = BN / 32;  // frags per wave (N)
  __shared__ ushort As[2][BM * 32];
  __shared__ ushort Bs[2][BN * 32];
  const int t = threadIdx.x, w = t >> 6, l = t & 63;
  const int m0 = blockIdx.y * BM, n0 = blockIdx.x * BN;
  const int wr = w >> 1, wc = w & 1;
  const int fr = l & 15, fq = l >> 4;
  const int sr = l >> 2, sc2 = (l & 3) * 8;
  const ushort* Ap = A + (size_t)blockIdx.z * aZ;
  const ushort* Bp = Bw + (size_t)blockIdx.z * bZ;

  auto stage = [&](int bb, int k0) {
#pragma unroll
    for (int g = w; g < AG + BG; g += 4) {
      if (g < AG) {
        int row = g * 16 + sr;
        gld16(Ap + (size_t)(m0 + row) * lda + k0 + sc2, (const char*)&As[bb][0] + g * 1024);
      } else {
        int gg = g - AG;
        int row = gg * 16 + sr;
        gld16(Bp + (size_t)(n0 + row) * ldb + k0 + sc2, (const char*)&Bs[bb][0] + gg * 1024);
      }
    }
  };

  f32x4 acc[MR][NR];
#pragma unroll
  for (int m = 0; m < MR; ++m)
#pragma unroll
    for (int n = 0; n < NR; ++n) acc[m][n] = (f32x4){0.f, 0.f, 0.f, 0.f};

  stage(0, 0);
  __syncthreads();  // implicit vmcnt(0) drain of prologue stage
  int cur = 0;
  const int nk = K / 32;
  for (int k = 0; k < nk; ++k) {
    if (k + 1 < nk) stage(cur ^ 1, (k + 1) * 32);  // prefetch next tile
    bf16x8 af[MR], bfr[NR];
#pragma unroll
    for (int m = 0; m < MR; ++m)
      af[m] = *(const bf16x8*)&As[cur][(wr * (BM / 2) + m * 16 + fr) * 32 + fq * 8];
#pragma unroll
    for (int n = 0; n < NR; ++n)
      bfr[n] = *(const bf16x8*)&Bs[cur][(wc * (BN / 2) + n * 16 + fr) * 32 + fq * 8];
#pragma unroll
    for (int m = 0; m < MR; ++m)
#pragma unroll
      for (int n = 0; n < NR; ++n)
        acc[m][n] = __builtin_amdgcn_mfma_f32_16x16x32_bf16(af[m], bfr[n], acc[m][n], 0, 0, 0);
    __syncthreads();  // drains prefetch (overlapped with compute above)
    cur ^= 1;
  }

#pragma unroll
  for (int m = 0; m < MR; ++m) {
#pragma unroll
    for (int n = 0; n < NR; ++n) {
      int col = n0 + wc * (BN / 2) + n * 16 + fr;
#pragma unroll
      for (int j = 0; j < 4; ++j) {
        int row = m0 + wr * (BM / 2) + m * 16 + fq * 4 + j;
        float v = acc[m][n][j];
        if (ADD_X) v += X[(size_t)row * ldx + col];
        if (OUT_BF16)
          ((ushort*)Cout + (size_t)blockIdx.z * cZ)[(size_t)row * ldc + col] = f2bs(v);
        else
          ((float*)Cout + (size_t)blockIdx.z * cZ)[(size_t)row * ldc + col] = v;
      }
    }
  }
}

// ---------------- causal (fwd) / anti-causal (bwd) depthwise conv + silu + dt ----------------
__global__ __launch_bounds__(256) void conv_dt_kernel(
    const float* __restrict__ zx,
    const float* __restrict__ cw0, const float* __restrict__ cb0,
    const float* __restrict__ dtb0, const float* __restrict__ Al0,
    const float* __restrict__ cw1, const float* __restrict__ cb1,
    const float* __restrict__ dtb1, const float* __restrict__ Al1,
    float* __restrict__ xbc, float* __restrict__ dta) {
  int m = blockIdx.x;
  int dir = blockIdx.y;
  int l = m & (SEQ - 1);
  const float* cw = dir ? cw1 : cw0;
  const float* cb = dir ? cb1 : cb0;
  const float* zrow = zx + (size_t)m * 6400 + dir * 3200 + DINNER;
  float* xo = xbc + ((size_t)dir * MROWS + m) * CONVDIM;
  for (int c = threadIdx.x; c < CONVDIM; c += 256) {
    float acc = cb[c];
    if (dir == 0) {
#pragma unroll
      for (int d = 0; d < 4; ++d) {
        if (l - d >= 0) acc = fmaf(zrow[-(size_t)d * 6400 + c], cw[c * 4 + 3 - d], acc);
      }
    } else {
#pragma unroll
      for (int d = 0; d < 4; ++d) {
        if (l + d < SEQ) acc = fmaf(zrow[(size_t)d * 6400 + c], cw[c * 4 + 3 - d], acc);
      }
    }
    xo[c] = acc / (1.f + expf(-acc));  // silu
  }
  if (threadIdx.x < NHEADS) {
    int hh = threadIdx.x;
    const float* dtb = dir ? dtb1 : dtb0;
    const float* Al = dir ? Al1 : Al0;
    float v = zx[(size_t)m * 6400 + dir * 3200 + DINNER + CONVDIM + hh] + dtb[hh];
    float dt = (v > 20.f) ? v : log1pf(expf(v));
    float A = -expf(Al[hh]);
    dta[((size_t)dir * MROWS + m) * 48 + hh] = dt;
    dta[((size_t)dir * MROWS + m) * 48 + NHEADS + hh] = expf(dt * A);
  }
}

// ---------------- scan phase 1: per-chunk local end-state and decay ----------------
__global__ __launch_bounds__(256) void scan_phase1(
    const float* __restrict__ xbc, const float* __restrict__ dta,
    float* __restrict__ sbuf, float* __restrict__ abuf) {
  __shared__ float xs[CL][64];
  __shared__ float bcs[CL][64];
  __shared__ float das[CL][2];
  int c = blockIdx.x, bh = blockIdx.y, dir = blockIdx.z;
  int b = bh / NHEADS, h = bh % NHEADS;
  int t = threadIdx.x, p = t >> 2, q = t & 3;
  const float* xb = xbc + ((size_t)dir * MROWS + b * SEQ) * CONVDIM;
  int lrow = t >> 4, lcol = (t & 15) * 4;
#pragma unroll
  for (int r = 0; r < 4; ++r) {
    int s = r * 16 + lrow;
    int tau = c * CL + s;
    int prow = dir ? (SEQ - 1 - tau) : tau;
    const float* rowp = xb + (size_t)prow * CONVDIM;
    *(float4*)&xs[s][lcol] = *(const float4*)(rowp + h * HEADDIM + lcol);
    *(float4*)&bcs[s][lcol] = *(const float4*)(rowp + DINNER + lcol);
  }
  if (t < 128) {
    int s = t >> 1, wsel = t & 1;
    int tau = c * CL + s;
    int prow = dir ? (SEQ - 1 - tau) : tau;
    das[s][wsel] = dta[((size_t)dir * MROWS + b * SEQ + prow) * 48 + wsel * NHEADS + h];
  }
  __syncthreads();
  float hst[8];
#pragma unroll
  for (int j = 0; j < 8; ++j) hst[j] = 0.f;
  float alpha = 1.f;
#pragma unroll 8
  for (int s = 0; s < CL; ++s) {
    float xp = xs[s][p];
    float dt_s = das[s][0], a_s = das[s][1];
    float cx = dt_s * xp;
    alpha *= a_s;
    float4 B0 = *(const float4*)&bcs[s][q * 8];
    float4 B1 = *(const float4*)&bcs[s][q * 8 + 4];
    float Bv[8] = {B0.x, B0.y, B0.z, B0.w, B1.x, B1.y, B1.z, B1.w};
#pragma unroll
    for (int j = 0; j < 8; ++j) hst[j] = fmaf(a_s, hst[j], cx * Bv[j]);
  }
  float* sp = sbuf + (((size_t)(dir * 48 + bh)) * NCH + c) * 2048 + p * 32 + q * 8;
#pragma unroll
  for (int j = 0; j < 8; ++j) sp[j] = hst[j];
  if (t == 0) abuf[(dir * 48 + bh) * NCH + c] = alpha;
}

// ---------------- scan phase 2: combine chunk states ----------------
__global__ __launch_bounds__(256) void scan_phase2(float* __restrict__ sbuf,
                                                   const float* __restrict__ abuf) {
  int g = blockIdx.x;
  int t = threadIdx.x;
  float run[8];
#pragma unroll
  for (int j = 0; j < 8; ++j) run[j] = 0.f;
  size_t base = (size_t)g * NCH * 2048 + t * 8;
  for (int c = 0; c < NCH; ++c) {
    float* sp = sbuf + base + (size_t)c * 2048;
    float4 s0 = *(const float4*)sp;
    float4 s1 = *(const float4*)(sp + 4);
    float al = abuf[g * NCH + c];
    float4 r0 = {run[0], run[1], run[2], run[3]};
    float4 r1 = {run[4], run[5], run[6], run[7]};
    *(float4*)sp = r0;
    *(float4*)(sp + 4) = r1;
    float sv[8] = {s0.x, s0.y, s0.z, s0.w, s1.x, s1.y, s1.z, s1.w};
#pragma unroll
    for (int j = 0; j < 8; ++j) run[j] = fmaf(al, run[j], sv[j]);
  }
}

// ---------------- scan phase 3: per-chunk recurrence from h0, write y ----------------
__global__ __launch_bounds__(256) void scan_phase3(
    const float* __restrict__ xbc, const float* __restrict__ dta,
    const float* __restrict__ sbuf,
    const float* __restrict__ Dp0, const float* __restrict__ Dp1,
    float* __restrict__ y) {
  __shared__ float xs[CL][64];
  __shared__ float bcs[CL][64];
  __shared__ float das[CL][2];
  int c = blockIdx.x, bh = blockIdx.y, dir = blockIdx.z;
  int b = bh / NHEADS, h = bh % NHEADS;
  int t = threadIdx.x, p = t >> 2, q = t & 3;
  const float* xb = xbc + ((size_t)dir * MROWS + b * SEQ) * CONVDIM;
  int lrow = t >> 4, lcol = (t & 15) * 4;
#pragma unroll
  for (int r = 0; r < 4; ++r) {
    int s = r * 16 + lrow;
    int tau = c * CL + s;
    int prow = dir ? (SEQ - 1 - tau) : tau;
    const float* rowp = xb + (size_t)prow * CONVDIM;
    *(float4*)&xs[s][lcol] = *(const float4*)(rowp + h * HEADDIM + lcol);
    *(float4*)&bcs[s][lcol] = *(const float4*)(rowp + DINNER + lcol);
  }
  if (t < 128) {
    int s = t >> 1, wsel = t & 1;
    int tau = c * CL + s;
    int prow = dir ? (SEQ - 1 - tau) : tau;
    das[s][wsel] = dta[((size_t)dir * MROWS + b * SEQ + prow) * 48 + wsel * NHEADS + h];
  }
  float hst[8];
  {
    const float* sp = sbuf + (((size_t)(dir * 48 + bh)) * NCH + c) * 2048 + p * 32 + q * 8;
    float4 h0 = *(const float4*)sp;
    float4 h1 = *(const float4*)(sp + 4);
    hst[0] = h0.x; hst[1] = h0.y; hst[2] = h0.z; hst[3] = h0.w;
    hst[4] = h1.x; hst[5] = h1.y; hst[6] = h1.z; hst[7] = h1.w;
  }
  float Dv = (dir ? Dp1 : Dp0)[h];
  __syncthreads();
#pragma unroll 8
  for (int s = 0; s < CL; ++s) {
    float xp = xs[s][p];
    float dt_s = das[s][0], a_s = das[s][1];
    float cx = dt_s * xp;
    float4 B0 = *(const float4*)&bcs[s][q * 8];
    float4 B1 = *(const float4*)&bcs[s][q * 8 + 4];
    float4 C0 = *(const float4*)&bcs[s][32 + q * 8];
    float4 C1 = *(const float4*)&bcs[s][32 + q * 8 + 4];
    float Bv[8] = {B0.x, B0.y, B0.z, B0.w, B1.x, B1.y, B1.z, B1.w};
    float Cv[8] = {C0.x, C0.y, C0.z, C0.w, C1.x, C1.y, C1.z, C1.w};
    float acc = 0.f;
#pragma unroll
    for (int j = 0; j < 8; ++j) {
      hst[j] = fmaf(a_s, hst[j], cx * Bv[j]);
      acc = fmaf(hst[j], Cv[j], acc);
    }
    acc += __shfl_xor(acc, 1, 64);
    acc += __shfl_xor(acc, 2, 64);
    if (q == 0) {
      int tau = c * CL + s;
      int prow = dir ? (SEQ - 1 - tau) : tau;
      y[((size_t)dir * MROWS + b * SEQ + prow) * DINNER + h * HEADDIM + p] = fmaf(Dv, xp, acc);
    }
  }
}

// ---------------- gated RMSNorm -> yn (bf16) ----------------
__global__ __launch_bounds__(256) void gated_norm_kernel(
    const float* __restrict__ y,
    const float* __restrict__ zx,
    const float* __restrict__ nw0, const float* __restrict__ nw1,
    ushort* __restrict__ yn) {
  __shared__ float ws4[4];
  int m = blockIdx.x;
  int dir = blockIdx.y;
  const float* nw = dir ? nw1 : nw0;
  float g[6];
  float ss = 0.f;
#pragma unroll
  for (int i = 0; i < 6; ++i) {
    int c = threadIdx.x + i * 256;
    float yv = y[((size_t)dir * MROWS + m) * DINNER + c];
    float zv = zx[(size_t)m * 6400 + dir * 3200 + c];
    float gg = yv * (zv / (1.f + expf(-zv)));
    g[i] = gg;
    ss += gg * gg;
  }
  ss = block_reduce_sum(ss, ws4);
  float sc = rsqrtf(ss / (float)DINNER + 1e-5f);
#pragma unroll
  for (int i = 0; i < 6; ++i) {
    int c = threadIdx.x + i * 256;
    yn[((size_t)dir * MROWS + m) * DINNER + c] = f2bs(g[i] * sc * nw[c]);
  }
}

// ---------------- launch ----------------
extern "C" void kernel_launch(void* const* d_in, const int* in_sizes, int n_in,
                              void* d_out, int out_size, void* d_ws, size_t ws_size,
                              hipStream_t stream) {
  const float* x = (const float*)d_in[0];
  const float* norm_w = (const float*)d_in[1];
  const float* in_w[2] = {(const float*)d_in[2], (const float*)d_in[10]};
  const float* conv_w[2] = {(const float*)d_in[3], (const float*)d_in[11]};
  const float* conv_b[2] = {(const float*)d_in[4], (const float*)d_in[12]};
  const float* dt_bias[2] = {(const float*)d_in[5], (const float*)d_in[13]};
  const float* A_log[2] = {(const float*)d_in[6], (const float*)d_in[14]};
  const float* Dp[2] = {(const float*)d_in[7], (const float*)d_in[15]};
  const float* nw[2] = {(const float*)d_in[8], (const float*)d_in[16]};
  const float* out_w[2] = {(const float*)d_in[9], (const float*)d_in[17]};
  const float* proj_w = (const float*)d_in[18];
  float* out = (float*)d_out;

  char* p = (char*)d_ws;
  float* zx = (float*)p;    p += (size_t)MROWS * 6400 * 4;
  float* xbc = (float*)p;   p += (size_t)2 * MROWS * CONVDIM * 4;
  float* dta = (float*)p;   p += (size_t)2 * MROWS * 48 * 4;
  float* y = (float*)p;     p += (size_t)2 * MROWS * DINNER * 4;
  float* sbuf = (float*)p;  p += (size_t)96 * NCH * 2048 * 4;
  float* abuf = (float*)p;  p += (size_t)96 * NCH * 4;
  ushort* h = (ushort*)p;   p += (size_t)MROWS * DMODEL * 2;
  ushort* yn = (ushort*)p;  p += (size_t)2 * MROWS * DINNER * 2;
  ushort* cat = (ushort*)p; p += (size_t)MROWS * DINNER * 2;
  ushort* wi = (ushort*)p;  p += (size_t)2 * NPAD * DMODEL * 2;   // contiguous: wi|wo|wp
  ushort* wo = (ushort*)p;  p += (size_t)2 * DMODEL * DINNER * 2;
  ushort* wp = (ushort*)p;  p += (size_t)DMODEL * DINNER * 2;

  // all weight conversions, one dispatch
  {
    size_t tot = 2 * (size_t)NPAD * DMODEL + 3 * (size_t)DMODEL * DINNER;
    f2b_all<<<(tot / 4 + 255) / 256, 256, 0, stream>>>(in_w[0], in_w[1], out_w[0], out_w[1],
                                                       proj_w, wi);
  }

  rmsnorm_in_kernel<<<MROWS, 256, 0, stream>>>(x, norm_w, h);

  // in_proj both dirs: zx[1024][6400] = h @ [wi0|wi1]^T
  {
    dim3 g(6400 / 128, MROWS / 128, 1);
    gemm2<128, 128, false, false><<<g, 256, 0, stream>>>(h, DMODEL, 0, wi, DMODEL, 0,
                                                         zx, 6400, 0, nullptr, 0, DMODEL);
  }

  conv_dt_kernel<<<dim3(MROWS, 2), 256, 0, stream>>>(
      zx, conv_w[0], conv_b[0], dt_bias[0], A_log[0],
      conv_w[1], conv_b[1], dt_bias[1], A_log[1], xbc, dta);

  scan_phase1<<<dim3(NCH, 48, 2), 256, 0, stream>>>(xbc, dta, sbuf, abuf);
  scan_phase2<<<96, 256, 0, stream>>>(sbuf, abuf);
  scan_phase3<<<dim3(NCH, 48, 2), 256, 0, stream>>>(xbc, dta, sbuf, Dp[0], Dp[1], y);

  gated_norm_kernel<<<dim3(MROWS, 2), 256, 0, stream>>>(y, zx, nw[0], nw[1], yn);

  // out_proj both dirs: cat[:, dir*768 +: 768] = yn[dir] @ wo[dir]^T  (128x64 tiles, 192 blocks)
  {
    dim3 g(DMODEL / 64, MROWS / 128, 2);
    gemm2<128, 64, false, true><<<g, 256, 0, stream>>>(
        yn, DINNER, (size_t)MROWS * DINNER, wo, DINNER, (size_t)DMODEL * DINNER,
        cat, DINNER, (size_t)DMODEL, nullptr, 0, DINNER);
  }

  // final: out = x + cat @ wp^T  (64x64 tiles, 192 blocks)
  {
    dim3 g(DMODEL / 64, MROWS / 64, 1);
    gemm2<64, 64, true, false><<<g, 256, 0, stream>>>(cat, DINNER, 0, wp, DINNER, 0,
                                                      out, DMODEL, 0, x, DMODEL, DINNER);
  }
}